// Round 13
// baseline (52.659 us; speedup 1.0000x reference)
//
#include <hip/hip_runtime.h>
#include <hip/hip_fp16.h>

#define Bdim 4
#define Cdim 128
#define Hdim 96
#define Wdim 96
#define HW   (Hdim*Wdim)        // 9216
#define NOC  18                 // rot conv output channels

typedef __attribute__((ext_vector_type(8))) short bf16x8;
typedef __attribute__((ext_vector_type(4))) float f32x4;
typedef _Float16 h2 __attribute__((ext_vector_type(2)));

__device__ inline short f2bf(float f) {          // round-to-nearest-even bf16
    unsigned u = __float_as_uint(f);
    unsigned r = (u + 0x7FFFu + ((u >> 16) & 1u)) >> 16;
    return (short)r;
}

__device__ inline unsigned pkh2(float a, float b) {   // (b<<16)|a as fp16 pair
    return (unsigned)__half_as_ushort(__float2half(a)) |
           ((unsigned)__half_as_ushort(__float2half(b)) << 16);
}

// ---------------------------------------------------------------------------
// Kernel 1 (prep): x -> bf16 NHWC xnh (halo-padded) + wpk A-fragments +
// packed fp16 weight-quad table wtab. IDENTICAL to R12 (control).
// ---------------------------------------------------------------------------
__global__ __launch_bounds__(256) void prep_kernel(const float* __restrict__ x,
                                                   const float* __restrict__ rot_w,
                                                   const float* __restrict__ weight,
                                                   short* __restrict__ xnh,
                                                   short* __restrict__ wpk,
                                                   uint4* __restrict__ wtab) {
    __shared__ short ldsT[96 * 72];   // [w][c_local], stride 72
    const int bid = blockIdx.x;
    const int t   = threadIdx.x;

    if (bid < 768) {
        int b = bid / 192;
        int h = (bid / 2) % 96;
        int c0 = (bid & 1) * 64;
        const float* xs = x + ((size_t)(b * Cdim + c0) * Hdim + h) * Wdim;
#pragma unroll
        for (int i = 0; i < 24; ++i) {
            int idx = i * 256 + t;           // 0..6143 = 64c x 96w
            int w  = idx % 96;
            int ci = idx / 96;
            ldsT[w * 72 + ci] = f2bf(xs[(size_t)ci * HW + w]);
        }
        __syncthreads();
        short* dst = xnh + (((size_t)b * 98 + (h + 1)) * 98 + 1) * 128 + c0;
#pragma unroll
        for (int j = 0; j < 3; ++j) {
            int idx = j * 256 + t;           // 0..767 = 96w x 8 c-groups
            int c8 = idx % 8;
            int w  = idx / 8;
            *(bf16x8*)(dst + (size_t)w * 128 + c8 * 8) = *(const bf16x8*)&ldsT[w * 72 + c8 * 8];
        }
    } else if (bid < 776) {
        int z = bid - 768;
        int b = z / 2;
        int r = (z & 1) ? 97 : 0;
        short* base = xnh + ((size_t)b * 98 + r) * 98 * 128;
        bf16x8 zero = {0,0,0,0,0,0,0,0};
        for (int i = t; i < 1568; i += 256)      // 1568*8 = 98*128
            ((bf16x8*)base)[i] = zero;
    } else if (bid < 784) {
        int z = bid - 776;
        int b = z / 2;
        int col = (z & 1) ? 97 : 0;
        bf16x8 zero = {0,0,0,0,0,0,0,0};
        for (int i = t; i < 1536; i += 256) {    // rows 1..96 x 16 c-groups
            int r  = 1 + i / 16;
            int c8 = i % 16;
            *(bf16x8*)(xnh + (((size_t)b * 98 + r) * 98 + col) * 128 + c8 * 8) = zero;
        }
    } else if (bid < 928) {
        int f = (bid - 784) * 256 + t;           // 0..36863
        int e    = f & 7;
        int l    = (f >> 3) & 63;
        int ch   = (f >> 9) & 3;
        int tap  = (f >> 11) % 9;
        int mt   = f / 18432;
        int oc = mt * 16 + (l & 15);
        int c  = ch * 32 + (l >> 4) * 8 + e;
        float v = (oc < NOC) ? rot_w[(size_t)oc * (Cdim * 9) + c * 9 + tap] : 0.f;
        wpk[f] = f2bf(v);
    } else {
        for (int i = t; i < 576; i += 256) {
            int e = i >> 6;              // cell 0..8
            int l = i & 63;              // c-pair
            int r = e / 3, s = e % 3;
            const float* w0p = weight + (size_t)(2 * l) * 16;
            uint4 v;
            v.x = pkh2(w0p[r * 4 + s],      w0p[r * 4 + s + 1]);
            v.y = pkh2(w0p[r * 4 + s + 4],  w0p[r * 4 + s + 5]);
            v.z = pkh2(w0p[16 + r * 4 + s],     w0p[16 + r * 4 + s + 1]);
            v.w = pkh2(w0p[16 + r * 4 + s + 4], w0p[16 + r * 4 + s + 5]);
            wtab[i] = v;
        }
    }
}

// ---------------------------------------------------------------------------
// Kernel 2: conv (bf16 MFMA implicit GEMM) with FUSED coef epilogue.
// MFMA body identical to R12. Epilogue format change only:
//   coefp[(b*HW+px)*9 + t] = uint2{ pk_f16(q00,q01), pk_f16(q10,q11) }
//   lidxp[b*HW+px].word[tq] = idx(t=3tq)|idx(3tq+1)<<8|idx(3tq+2)<<16
// ---------------------------------------------------------------------------
__global__ __launch_bounds__(256, 2) void conv_mfma(const short* __restrict__ xnh,
                                                    const short* __restrict__ wpk,
                                                    const float* __restrict__ rot_b,
                                                    uint2* __restrict__ coefp,
                                                    uint4* __restrict__ lidxp) {
    __shared__ short wlds[36864];                // 72 KB A-fragments
    __shared__ float dsc[64 * 20];               // 5 KB per-wave D scratch
    const int tid  = threadIdx.x;
    const int lane = tid & 63;
    const int wid  = tid >> 6;
    for (int i = tid; i < 4608; i += 256)
        ((bf16x8*)wlds)[i] = ((const bf16x8*)wpk)[i];
    __syncthreads();

    const int ntile = blockIdx.x * 4 + wid;      // 0..2303
    const int b   = ntile / 576;
    const int hw0 = (ntile % 576) * 16;
    const int h   = hw0 / Wdim;
    const int w0  = hw0 % Wdim;
    const int px = lane & 15, kg = lane >> 4;

    f32x4 a00 = {0,0,0,0}, a01 = {0,0,0,0};
    f32x4 a10 = {0,0,0,0}, a11 = {0,0,0,0};
    const short* xb = xnh + (((size_t)b * 98 + h) * 98 + (w0 + px)) * 128 + kg * 8;
    const short* wl = wlds + lane * 8;

    bf16x8 Bc[4], A0c[4], A1c[4];
#pragma unroll
    for (int ch = 0; ch < 4; ++ch) {             // preload tap 0
        Bc[ch]  = *(const bf16x8*)(xb + ch * 32);
        A0c[ch] = *(const bf16x8*)(wl + ch * 512);
        A1c[ch] = *(const bf16x8*)(wl + (36 + ch) * 512);
    }

#pragma unroll
    for (int tap = 0; tap < 9; ++tap) {
        bf16x8 Bn[4], A0n[4], A1n[4];
        if (tap < 8) {
            const int di = (tap + 1) / 3, dj = (tap + 1) % 3;
            const short* xr = xb + (di * 98 + dj) * 128;
#pragma unroll
            for (int ch = 0; ch < 4; ++ch) {
                Bn[ch]  = *(const bf16x8*)(xr + ch * 32);
                A0n[ch] = *(const bf16x8*)(wl + ((tap + 1) * 4 + ch) * 512);
                A1n[ch] = *(const bf16x8*)(wl + ((9 + tap + 1) * 4 + ch) * 512);
            }
        }
        a00 = __builtin_amdgcn_mfma_f32_16x16x32_bf16(A0c[0], Bc[0], a00, 0, 0, 0);
        a10 = __builtin_amdgcn_mfma_f32_16x16x32_bf16(A1c[0], Bc[0], a10, 0, 0, 0);
        a01 = __builtin_amdgcn_mfma_f32_16x16x32_bf16(A0c[1], Bc[1], a01, 0, 0, 0);
        a11 = __builtin_amdgcn_mfma_f32_16x16x32_bf16(A1c[1], Bc[1], a11, 0, 0, 0);
        a00 = __builtin_amdgcn_mfma_f32_16x16x32_bf16(A0c[2], Bc[2], a00, 0, 0, 0);
        a10 = __builtin_amdgcn_mfma_f32_16x16x32_bf16(A1c[2], Bc[2], a10, 0, 0, 0);
        a01 = __builtin_amdgcn_mfma_f32_16x16x32_bf16(A0c[3], Bc[3], a01, 0, 0, 0);
        a11 = __builtin_amdgcn_mfma_f32_16x16x32_bf16(A1c[3], Bc[3], a11, 0, 0, 0);
        if (tap < 8) {
#pragma unroll
            for (int ch = 0; ch < 4; ++ch) { Bc[ch] = Bn[ch]; A0c[ch] = A0n[ch]; A1c[ch] = A1n[ch]; }
        }
    }
    f32x4 acc0 = a00 + a01;
    f32x4 acc1 = a10 + a11;

    // ---- fused coef epilogue (per-wave, no barrier) ----
    float* ds = dsc + (wid * 16) * 20;
    *(f32x4*)(ds + px * 20 + kg * 4) = acc0;
    if (kg == 0) {
        ds[px * 20 + 16] = acc1[0];
        ds[px * 20 + 17] = acc1[1];
    }
    __builtin_amdgcn_wave_barrier();

    const int px2 = lane & 15, tq = lane >> 4;
    if (tq < 3) {
        const float* dr = ds + px2 * 20;
        const int hwp = hw0 + px2;
        unsigned lword = 0u;
#pragma unroll
        for (int k = 0; k < 3; ++k) {
            int tt = tq * 3 + k;
            int i = tt / 3, j = tt % 3;
            float ch = dr[2 * tt]     + rot_b[2 * tt]     + (0.5f + (float)i);
            float cw = dr[2 * tt + 1] + rot_b[2 * tt + 1] + (0.5f + (float)j);
            ch = fminf(fmaxf(ch, 0.f), 3.f);
            cw = fminf(fmaxf(cw, 0.f), 3.f);
            float h0f = floorf(ch), w0f = floorf(cw);
            float lh = ch - h0f, lw = cw - w0f;
            int h0 = (int)h0f, w0i = (int)w0f;
            float bh0 = 1.f - lh;
            float aw0 = 1.f - lw;
            if (h0 >= 3)  { h0 = 2;  bh0 = 0.f; }
            if (w0i >= 3) { w0i = 2; aw0 = 0.f; }
            float q00 = aw0 * bh0;
            float q01 = (1.f - aw0) * bh0;
            float q10 = aw0 * (1.f - bh0);
            float q11 = (1.f - aw0) * (1.f - bh0);
            uint2 cf;
            cf.x = pkh2(q00, q01);
            cf.y = pkh2(q10, q11);
            coefp[((size_t)b * HW + hwp) * 9 + tt] = cf;
            lword |= (unsigned)(h0 * 3 + w0i) << (8 * k);
        }
        ((unsigned*)&lidxp[(size_t)b * HW + hwp])[tq] = lword;
    }
}

// ---------------------------------------------------------------------------
// Kernel 3: apply. Same structure as R12 EXCEPT the per-tap index comes from
// ONE uniform LDS word per pixel (packed by conv) -> all 9 table reads and 9
// coef reads have addresses known up-front and issue back-to-back (counted
// lgkm waits, overlapped latency) instead of a 260cy dependent chain per tap.
// ---------------------------------------------------------------------------
__global__ __launch_bounds__(256) void apply_kernel(const short* __restrict__ xnh,
                                                    const uint2* __restrict__ coefp,
                                                    const uint4* __restrict__ lidxp,
                                                    const uint4* __restrict__ wtab,
                                                    float* __restrict__ out) {
    __shared__ uint4 wq4[9][64];     // [cell][c-pair]  (9216 B)
    __shared__ uint2 cq2[144];       // coef pairs, 16px x 9taps (1152 B)
    __shared__ uint4 lid4[16];       // packed cell indices per px (256 B)
    __shared__ float ot[16][130];    // [px][c] store-transpose scratch
    const int tid  = threadIdx.x;
    const int lane = tid & 63;
    const int wv   = tid >> 6;       // 0..3

    for (int i = tid; i < 576; i += 256)          // coalesced b128 copy
        ((uint4*)wq4)[i] = wtab[i];
    if (tid < 144)
        cq2[tid] = coefp[(size_t)blockIdx.x * 144 + tid];
    if (tid < 16)
        lid4[tid] = lidxp[(size_t)blockIdx.x * 16 + tid];
    __syncthreads();

    const int bpx = blockIdx.x * 16;             // 16 consecutive px, same row
    const int b   = bpx / HW;
    const int hw0 = bpx % HW;
    const int h   = hw0 / Wdim;
    const int w0  = hw0 % Wdim;

    // register x window: rows h..h+2, cols (w0+4*wv)..(w0+4*wv+5), ch pair 2*lane
    const unsigned* xbase =
        (const unsigned*)(xnh + (((size_t)b * 98 + h) * 98 + (w0 + 4 * wv)) * 128) + lane;
    unsigned xw[3][6];
#pragma unroll
    for (int r = 0; r < 3; ++r)
#pragma unroll
        for (int j = 0; j < 6; ++j)
            xw[r][j] = xbase[(r * 98 + j) * 64];

    float acc0[4], acc1[4];
#pragma unroll
    for (int p = 0; p < 4; ++p) { acc0[p] = 0.f; acc1[p] = 0.f; }

#pragma unroll
    for (int pp = 0; pp < 4; ++pp) {
        const int p = 4 * wv + pp;
        uint4 lw = lid4[p];                      // ONE uniform read -> all indices
        const uint2* cp = &cq2[p * 9];
#pragma unroll
        for (int t = 0; t < 9; ++t) {
            unsigned idx = (((const unsigned*)&lw)[t / 3] >> (8 * (t % 3))) & 0xFu;
            uint4 g  = wq4[idx][lane];           // independent ds_read_b128
            uint2 cf = cp[t];                    // independent uniform ds_read_b64
            unsigned xu = xw[t / 3][pp + (t % 3)];
            float x0 = __uint_as_float(xu << 16);
            float x1 = __uint_as_float(xu & 0xFFFF0000u);
            float s0 = __builtin_amdgcn_fdot2(__builtin_bit_cast(h2, cf.x),
                                              __builtin_bit_cast(h2, g.x), 0.f, false);
            s0 = __builtin_amdgcn_fdot2(__builtin_bit_cast(h2, cf.y),
                                        __builtin_bit_cast(h2, g.y), s0, false);
            float s1 = __builtin_amdgcn_fdot2(__builtin_bit_cast(h2, cf.x),
                                              __builtin_bit_cast(h2, g.z), 0.f, false);
            s1 = __builtin_amdgcn_fdot2(__builtin_bit_cast(h2, cf.y),
                                        __builtin_bit_cast(h2, g.w), s1, false);
            acc0[pp] = fmaf(s0, x0, acc0[pp]);
            acc1[pp] = fmaf(s1, x1, acc1[pp]);
        }
    }

    // transpose through LDS: write [px][c] (float2, 2-way banks = free)
#pragma unroll
    for (int pp = 0; pp < 4; ++pp)
        *(float2*)&ot[4 * wv + pp][2 * lane] = make_float2(acc0[pp], acc1[pp]);
    __syncthreads();

    const int px = tid & 15;
    const int cr = tid >> 4;                     // 0..15
    float* ob = out + (size_t)b * Cdim * HW + hw0 + px;
#pragma unroll
    for (int k = 0; k < 8; ++k) {
        int ci = cr * 8 + k;
        ob[(size_t)ci * HW] = ot[px][ci];
    }
}

// ---------------------------------------------------------------------------
extern "C" void kernel_launch(void* const* d_in, const int* in_sizes, int n_in,
                              void* d_out, int out_size, void* d_ws, size_t ws_size,
                              hipStream_t stream) {
    const float* x      = (const float*)d_in[0];
    const float* rot_w  = (const float*)d_in[1];
    const float* rot_b  = (const float*)d_in[2];
    const float* weight = (const float*)d_in[3];
    float* out = (float*)d_out;

    char* ws = (char*)d_ws;
    const size_t xnh_bytes   = (size_t)Bdim * 98 * 98 * 128 * 2;   // 9,834,496
    const size_t wpk_bytes   = (size_t)2 * 9 * 4 * 64 * 8 * 2;     //    73,728
    const size_t coefp_bytes = (size_t)Bdim * HW * 9 * 8;          // 2,654,208
    const size_t lidx_bytes  = (size_t)Bdim * HW * 16;             //   589,824

    short* xnh   = (short*)ws;
    short* wpk   = (short*)(ws + xnh_bytes);
    uint2* coefp = (uint2*)(ws + xnh_bytes + wpk_bytes);
    uint4* lidxp = (uint4*)(ws + xnh_bytes + wpk_bytes + coefp_bytes);
    uint4* wtab  = (uint4*)(ws + xnh_bytes + wpk_bytes + coefp_bytes + lidx_bytes); // 9,216 B

    prep_kernel<<<929, 256, 0, stream>>>(x, rot_w, weight, xnh, wpk, wtab);
    conv_mfma<<<576, 256, 0, stream>>>(xnh, wpk, rot_b, coefp, lidxp);
    apply_kernel<<<2304, 256, 0, stream>>>(xnh, coefp, lidxp, wtab, out);
}

// Round 14
// 51.665 us; speedup vs baseline: 1.0192x; 1.0192x over previous
//
#include <hip/hip_runtime.h>
#include <hip/hip_fp16.h>

#define Bdim 4
#define Cdim 128
#define Hdim 96
#define Wdim 96
#define HW   (Hdim*Wdim)        // 9216
#define NOC  18                 // rot conv output channels

typedef __attribute__((ext_vector_type(8))) short bf16x8;
typedef __attribute__((ext_vector_type(4))) float f32x4;
typedef _Float16 h2 __attribute__((ext_vector_type(2)));

__device__ inline short f2bf(float f) {          // round-to-nearest-even bf16
    unsigned u = __float_as_uint(f);
    unsigned r = (u + 0x7FFFu + ((u >> 16) & 1u)) >> 16;
    return (short)r;
}

__device__ inline unsigned pkh2(float a, float b) {   // (b<<16)|a as fp16 pair
    return (unsigned)__half_as_ushort(__float2half(a)) |
           ((unsigned)__half_as_ushort(__float2half(b)) << 16);
}

// ---------------------------------------------------------------------------
// Kernel 1 (prep): x -> bf16 NHWC xnh (halo-padded) + wpk A-fragments +
// packed fp16 weight-quad table wtab. IDENTICAL to R13 (control).
// ---------------------------------------------------------------------------
__global__ __launch_bounds__(256) void prep_kernel(const float* __restrict__ x,
                                                   const float* __restrict__ rot_w,
                                                   const float* __restrict__ weight,
                                                   short* __restrict__ xnh,
                                                   short* __restrict__ wpk,
                                                   uint4* __restrict__ wtab) {
    __shared__ short ldsT[96 * 72];   // [w][c_local], stride 72
    const int bid = blockIdx.x;
    const int t   = threadIdx.x;

    if (bid < 768) {
        int b = bid / 192;
        int h = (bid / 2) % 96;
        int c0 = (bid & 1) * 64;
        const float* xs = x + ((size_t)(b * Cdim + c0) * Hdim + h) * Wdim;
#pragma unroll
        for (int i = 0; i < 24; ++i) {
            int idx = i * 256 + t;           // 0..6143 = 64c x 96w
            int w  = idx % 96;
            int ci = idx / 96;
            ldsT[w * 72 + ci] = f2bf(xs[(size_t)ci * HW + w]);
        }
        __syncthreads();
        short* dst = xnh + (((size_t)b * 98 + (h + 1)) * 98 + 1) * 128 + c0;
#pragma unroll
        for (int j = 0; j < 3; ++j) {
            int idx = j * 256 + t;           // 0..767 = 96w x 8 c-groups
            int c8 = idx % 8;
            int w  = idx / 8;
            *(bf16x8*)(dst + (size_t)w * 128 + c8 * 8) = *(const bf16x8*)&ldsT[w * 72 + c8 * 8];
        }
    } else if (bid < 776) {
        int z = bid - 768;
        int b = z / 2;
        int r = (z & 1) ? 97 : 0;
        short* base = xnh + ((size_t)b * 98 + r) * 98 * 128;
        bf16x8 zero = {0,0,0,0,0,0,0,0};
        for (int i = t; i < 1568; i += 256)      // 1568*8 = 98*128
            ((bf16x8*)base)[i] = zero;
    } else if (bid < 784) {
        int z = bid - 776;
        int b = z / 2;
        int col = (z & 1) ? 97 : 0;
        bf16x8 zero = {0,0,0,0,0,0,0,0};
        for (int i = t; i < 1536; i += 256) {    // rows 1..96 x 16 c-groups
            int r  = 1 + i / 16;
            int c8 = i % 16;
            *(bf16x8*)(xnh + (((size_t)b * 98 + r) * 98 + col) * 128 + c8 * 8) = zero;
        }
    } else if (bid < 928) {
        int f = (bid - 784) * 256 + t;           // 0..36863
        int e    = f & 7;
        int l    = (f >> 3) & 63;
        int ch   = (f >> 9) & 3;
        int tap  = (f >> 11) % 9;
        int mt   = f / 18432;
        int oc = mt * 16 + (l & 15);
        int c  = ch * 32 + (l >> 4) * 8 + e;
        float v = (oc < NOC) ? rot_w[(size_t)oc * (Cdim * 9) + c * 9 + tap] : 0.f;
        wpk[f] = f2bf(v);
    } else {
        for (int i = t; i < 576; i += 256) {
            int e = i >> 6;              // cell 0..8
            int l = i & 63;              // c-pair
            int r = e / 3, s = e % 3;
            const float* w0p = weight + (size_t)(2 * l) * 16;
            uint4 v;
            v.x = pkh2(w0p[r * 4 + s],      w0p[r * 4 + s + 1]);
            v.y = pkh2(w0p[r * 4 + s + 4],  w0p[r * 4 + s + 5]);
            v.z = pkh2(w0p[16 + r * 4 + s],     w0p[16 + r * 4 + s + 1]);
            v.w = pkh2(w0p[16 + r * 4 + s + 4], w0p[16 + r * 4 + s + 5]);
            wtab[i] = v;
        }
    }
}

// ---------------------------------------------------------------------------
// Kernel 2: conv (bf16 MFMA implicit GEMM) with FUSED coef epilogue.
// IDENTICAL to R13 (control).
// ---------------------------------------------------------------------------
__global__ __launch_bounds__(256, 2) void conv_mfma(const short* __restrict__ xnh,
                                                    const short* __restrict__ wpk,
                                                    const float* __restrict__ rot_b,
                                                    uint2* __restrict__ coefp,
                                                    uint4* __restrict__ lidxp) {
    __shared__ short wlds[36864];                // 72 KB A-fragments
    __shared__ float dsc[64 * 20];               // 5 KB per-wave D scratch
    const int tid  = threadIdx.x;
    const int lane = tid & 63;
    const int wid  = tid >> 6;
    for (int i = tid; i < 4608; i += 256)
        ((bf16x8*)wlds)[i] = ((const bf16x8*)wpk)[i];
    __syncthreads();

    const int ntile = blockIdx.x * 4 + wid;      // 0..2303
    const int b   = ntile / 576;
    const int hw0 = (ntile % 576) * 16;
    const int h   = hw0 / Wdim;
    const int w0  = hw0 % Wdim;
    const int px = lane & 15, kg = lane >> 4;

    f32x4 a00 = {0,0,0,0}, a01 = {0,0,0,0};
    f32x4 a10 = {0,0,0,0}, a11 = {0,0,0,0};
    const short* xb = xnh + (((size_t)b * 98 + h) * 98 + (w0 + px)) * 128 + kg * 8;
    const short* wl = wlds + lane * 8;

    bf16x8 Bc[4], A0c[4], A1c[4];
#pragma unroll
    for (int ch = 0; ch < 4; ++ch) {             // preload tap 0
        Bc[ch]  = *(const bf16x8*)(xb + ch * 32);
        A0c[ch] = *(const bf16x8*)(wl + ch * 512);
        A1c[ch] = *(const bf16x8*)(wl + (36 + ch) * 512);
    }

#pragma unroll
    for (int tap = 0; tap < 9; ++tap) {
        bf16x8 Bn[4], A0n[4], A1n[4];
        if (tap < 8) {
            const int di = (tap + 1) / 3, dj = (tap + 1) % 3;
            const short* xr = xb + (di * 98 + dj) * 128;
#pragma unroll
            for (int ch = 0; ch < 4; ++ch) {
                Bn[ch]  = *(const bf16x8*)(xr + ch * 32);
                A0n[ch] = *(const bf16x8*)(wl + ((tap + 1) * 4 + ch) * 512);
                A1n[ch] = *(const bf16x8*)(wl + ((9 + tap + 1) * 4 + ch) * 512);
            }
        }
        a00 = __builtin_amdgcn_mfma_f32_16x16x32_bf16(A0c[0], Bc[0], a00, 0, 0, 0);
        a10 = __builtin_amdgcn_mfma_f32_16x16x32_bf16(A1c[0], Bc[0], a10, 0, 0, 0);
        a01 = __builtin_amdgcn_mfma_f32_16x16x32_bf16(A0c[1], Bc[1], a01, 0, 0, 0);
        a11 = __builtin_amdgcn_mfma_f32_16x16x32_bf16(A1c[1], Bc[1], a11, 0, 0, 0);
        a00 = __builtin_amdgcn_mfma_f32_16x16x32_bf16(A0c[2], Bc[2], a00, 0, 0, 0);
        a10 = __builtin_amdgcn_mfma_f32_16x16x32_bf16(A1c[2], Bc[2], a10, 0, 0, 0);
        a01 = __builtin_amdgcn_mfma_f32_16x16x32_bf16(A0c[3], Bc[3], a01, 0, 0, 0);
        a11 = __builtin_amdgcn_mfma_f32_16x16x32_bf16(A1c[3], Bc[3], a11, 0, 0, 0);
        if (tap < 8) {
#pragma unroll
            for (int ch = 0; ch < 4; ++ch) { Bc[ch] = Bn[ch]; A0c[ch] = A0n[ch]; A1c[ch] = A1n[ch]; }
        }
    }
    f32x4 acc0 = a00 + a01;
    f32x4 acc1 = a10 + a11;

    // ---- fused coef epilogue (per-wave, no barrier) ----
    float* ds = dsc + (wid * 16) * 20;
    *(f32x4*)(ds + px * 20 + kg * 4) = acc0;
    if (kg == 0) {
        ds[px * 20 + 16] = acc1[0];
        ds[px * 20 + 17] = acc1[1];
    }
    __builtin_amdgcn_wave_barrier();

    const int px2 = lane & 15, tq = lane >> 4;
    if (tq < 3) {
        const float* dr = ds + px2 * 20;
        const int hwp = hw0 + px2;
        unsigned lword = 0u;
#pragma unroll
        for (int k = 0; k < 3; ++k) {
            int tt = tq * 3 + k;
            int i = tt / 3, j = tt % 3;
            float ch = dr[2 * tt]     + rot_b[2 * tt]     + (0.5f + (float)i);
            float cw = dr[2 * tt + 1] + rot_b[2 * tt + 1] + (0.5f + (float)j);
            ch = fminf(fmaxf(ch, 0.f), 3.f);
            cw = fminf(fmaxf(cw, 0.f), 3.f);
            float h0f = floorf(ch), w0f = floorf(cw);
            float lh = ch - h0f, lw = cw - w0f;
            int h0 = (int)h0f, w0i = (int)w0f;
            float bh0 = 1.f - lh;
            float aw0 = 1.f - lw;
            if (h0 >= 3)  { h0 = 2;  bh0 = 0.f; }
            if (w0i >= 3) { w0i = 2; aw0 = 0.f; }
            float q00 = aw0 * bh0;
            float q01 = (1.f - aw0) * bh0;
            float q10 = aw0 * (1.f - bh0);
            float q11 = (1.f - aw0) * (1.f - bh0);
            uint2 cf;
            cf.x = pkh2(q00, q01);
            cf.y = pkh2(q10, q11);
            coefp[((size_t)b * HW + hwp) * 9 + tt] = cf;
            lword |= (unsigned)(h0 * 3 + w0i) << (8 * k);
        }
        ((unsigned*)&lidxp[(size_t)b * HW + hwp])[tq] = lword;
    }
}

// ---------------------------------------------------------------------------
// Kernel 3: apply. 1152 blocks x 2 tiles: wtab staged ONCE per block
// (amortized), per-tile coef staging is 1.4 KB. Inner loop batches all 9
// table quads + 9 coef pairs into registers (independent LDS ops, one wait)
// before the 36 fdot2+fma — no serialized 120cy LDS chain.
// ---------------------------------------------------------------------------
__global__ __launch_bounds__(256) void apply_kernel(const short* __restrict__ xnh,
                                                    const uint2* __restrict__ coefp,
                                                    const uint4* __restrict__ lidxp,
                                                    const uint4* __restrict__ wtab,
                                                    float* __restrict__ out) {
    __shared__ uint4 wq4[9][64];     // [cell][c-pair]  (9216 B)
    __shared__ uint2 cq2[144];       // coef pairs, 16px x 9taps (1152 B)
    __shared__ uint4 lid4[16];       // packed cell indices per px (256 B)
    __shared__ float ot[16][130];    // [px][c] store-transpose scratch
    const int tid  = threadIdx.x;
    const int lane = tid & 63;
    const int wv   = tid >> 6;       // 0..3

    for (int i = tid; i < 576; i += 256)          // stage wtab ONCE per block
        ((uint4*)wq4)[i] = wtab[i];

#pragma unroll
    for (int it = 0; it < 2; ++it) {
        const int tile = blockIdx.x * 2 + it;     // 0..2303
        // stage this tile's coefs (parallel thread groups)
        if (tid < 144)
            cq2[tid] = coefp[(size_t)tile * 144 + tid];
        else if (tid >= 160 && tid < 176)
            lid4[tid - 160] = lidxp[(size_t)tile * 16 + (tid - 160)];
        __syncthreads();

        const int bpx = tile * 16;               // 16 consecutive px, same row
        const int b   = bpx / HW;
        const int hw0 = bpx % HW;
        const int h   = hw0 / Wdim;
        const int w0  = hw0 % Wdim;

        // register x window: rows h..h+2, cols (w0+4wv)..(w0+4wv+5), ch pair 2*lane
        const unsigned* xbase =
            (const unsigned*)(xnh + (((size_t)b * 98 + h) * 98 + (w0 + 4 * wv)) * 128) + lane;
        unsigned xw[3][6];
#pragma unroll
        for (int r = 0; r < 3; ++r)
#pragma unroll
            for (int j = 0; j < 6; ++j)
                xw[r][j] = xbase[(r * 98 + j) * 64];

        float acc0[4], acc1[4];
#pragma unroll
        for (int p = 0; p < 4; ++p) { acc0[p] = 0.f; acc1[p] = 0.f; }

#pragma unroll
        for (int pp = 0; pp < 4; ++pp) {
            const int p = 4 * wv + pp;
            uint4 lw = lid4[p];                  // one uniform read -> all indices
            uint4 g[9];
            uint2 cf[9];
#pragma unroll
            for (int t = 0; t < 9; ++t) {        // batched independent LDS reads
                unsigned idx = (((const unsigned*)&lw)[t / 3] >> (8 * (t % 3))) & 0xFu;
                g[t]  = wq4[idx][lane];
                cf[t] = cq2[p * 9 + t];
            }
#pragma unroll
            for (int t = 0; t < 9; ++t) {
                unsigned xu = xw[t / 3][pp + (t % 3)];
                float x0 = __uint_as_float(xu << 16);
                float x1 = __uint_as_float(xu & 0xFFFF0000u);
                float s0 = __builtin_amdgcn_fdot2(__builtin_bit_cast(h2, cf[t].x),
                                                  __builtin_bit_cast(h2, g[t].x), 0.f, false);
                s0 = __builtin_amdgcn_fdot2(__builtin_bit_cast(h2, cf[t].y),
                                            __builtin_bit_cast(h2, g[t].y), s0, false);
                float s1 = __builtin_amdgcn_fdot2(__builtin_bit_cast(h2, cf[t].x),
                                                  __builtin_bit_cast(h2, g[t].z), 0.f, false);
                s1 = __builtin_amdgcn_fdot2(__builtin_bit_cast(h2, cf[t].y),
                                            __builtin_bit_cast(h2, g[t].w), s1, false);
                acc0[pp] = fmaf(s0, x0, acc0[pp]);
                acc1[pp] = fmaf(s1, x1, acc1[pp]);
            }
        }

        // transpose through LDS: write [px][c] (float2, 2-way banks = free)
#pragma unroll
        for (int pp = 0; pp < 4; ++pp)
            *(float2*)&ot[4 * wv + pp][2 * lane] = make_float2(acc0[pp], acc1[pp]);
        __syncthreads();

        const int px = tid & 15;
        const int cr = tid >> 4;                 // 0..15
        float* ob = out + (size_t)b * Cdim * HW + hw0 + px;
#pragma unroll
        for (int k = 0; k < 8; ++k) {
            int ci = cr * 8 + k;
            ob[(size_t)ci * HW] = ot[px][ci];
        }
    }
}

// ---------------------------------------------------------------------------
extern "C" void kernel_launch(void* const* d_in, const int* in_sizes, int n_in,
                              void* d_out, int out_size, void* d_ws, size_t ws_size,
                              hipStream_t stream) {
    const float* x      = (const float*)d_in[0];
    const float* rot_w  = (const float*)d_in[1];
    const float* rot_b  = (const float*)d_in[2];
    const float* weight = (const float*)d_in[3];
    float* out = (float*)d_out;

    char* ws = (char*)d_ws;
    const size_t xnh_bytes   = (size_t)Bdim * 98 * 98 * 128 * 2;   // 9,834,496
    const size_t wpk_bytes   = (size_t)2 * 9 * 4 * 64 * 8 * 2;     //    73,728
    const size_t coefp_bytes = (size_t)Bdim * HW * 9 * 8;          // 2,654,208
    const size_t lidx_bytes  = (size_t)Bdim * HW * 16;             //   589,824

    short* xnh   = (short*)ws;
    short* wpk   = (short*)(ws + xnh_bytes);
    uint2* coefp = (uint2*)(ws + xnh_bytes + wpk_bytes);
    uint4* lidxp = (uint4*)(ws + xnh_bytes + wpk_bytes + coefp_bytes);
    uint4* wtab  = (uint4*)(ws + xnh_bytes + wpk_bytes + coefp_bytes + lidx_bytes); // 9,216 B

    prep_kernel<<<929, 256, 0, stream>>>(x, rot_w, weight, xnh, wpk, wtab);
    conv_mfma<<<576, 256, 0, stream>>>(xnh, wpk, rot_b, coefp, lidxp);
    apply_kernel<<<1152, 256, 0, stream>>>(xnh, coefp, lidxp, wtab, out);
}

// Round 15
// 36.523 us; speedup vs baseline: 1.4418x; 1.4146x over previous
//
#include <hip/hip_runtime.h>
#include <hip/hip_fp16.h>

#define Bdim 4
#define Cdim 128
#define Hdim 96
#define Wdim 96
#define HW   (Hdim*Wdim)        // 9216
#define NOC  18                 // rot conv output channels

typedef __attribute__((ext_vector_type(8))) short bf16x8;
typedef __attribute__((ext_vector_type(4))) float f32x4;
typedef _Float16 h2 __attribute__((ext_vector_type(2)));

__device__ inline short f2bf(float f) {          // round-to-nearest-even bf16
    unsigned u = __float_as_uint(f);
    unsigned r = (u + 0x7FFFu + ((u >> 16) & 1u)) >> 16;
    return (short)r;
}

__device__ inline unsigned pkh2(float a, float b) {   // (b<<16)|a as fp16 pair
    return (unsigned)__half_as_ushort(__float2half(a)) |
           ((unsigned)__half_as_ushort(__float2half(b)) << 16);
}

// ---------------------------------------------------------------------------
// Kernel 1 (prep): x -> bf16 NHWC xnh (halo-padded) + wpk A-fragments +
// packed fp16 weight-quad table wtab. IDENTICAL to R14 (control).
// ---------------------------------------------------------------------------
__global__ __launch_bounds__(256) void prep_kernel(const float* __restrict__ x,
                                                   const float* __restrict__ rot_w,
                                                   const float* __restrict__ weight,
                                                   short* __restrict__ xnh,
                                                   short* __restrict__ wpk,
                                                   uint4* __restrict__ wtab) {
    __shared__ short ldsT[96 * 72];   // [w][c_local], stride 72
    const int bid = blockIdx.x;
    const int t   = threadIdx.x;

    if (bid < 768) {
        int b = bid / 192;
        int h = (bid / 2) % 96;
        int c0 = (bid & 1) * 64;
        const float* xs = x + ((size_t)(b * Cdim + c0) * Hdim + h) * Wdim;
#pragma unroll
        for (int i = 0; i < 24; ++i) {
            int idx = i * 256 + t;           // 0..6143 = 64c x 96w
            int w  = idx % 96;
            int ci = idx / 96;
            ldsT[w * 72 + ci] = f2bf(xs[(size_t)ci * HW + w]);
        }
        __syncthreads();
        short* dst = xnh + (((size_t)b * 98 + (h + 1)) * 98 + 1) * 128 + c0;
#pragma unroll
        for (int j = 0; j < 3; ++j) {
            int idx = j * 256 + t;           // 0..767 = 96w x 8 c-groups
            int c8 = idx % 8;
            int w  = idx / 8;
            *(bf16x8*)(dst + (size_t)w * 128 + c8 * 8) = *(const bf16x8*)&ldsT[w * 72 + c8 * 8];
        }
    } else if (bid < 776) {
        int z = bid - 768;
        int b = z / 2;
        int r = (z & 1) ? 97 : 0;
        short* base = xnh + ((size_t)b * 98 + r) * 98 * 128;
        bf16x8 zero = {0,0,0,0,0,0,0,0};
        for (int i = t; i < 1568; i += 256)      // 1568*8 = 98*128
            ((bf16x8*)base)[i] = zero;
    } else if (bid < 784) {
        int z = bid - 776;
        int b = z / 2;
        int col = (z & 1) ? 97 : 0;
        bf16x8 zero = {0,0,0,0,0,0,0,0};
        for (int i = t; i < 1536; i += 256) {    // rows 1..96 x 16 c-groups
            int r  = 1 + i / 16;
            int c8 = i % 16;
            *(bf16x8*)(xnh + (((size_t)b * 98 + r) * 98 + col) * 128 + c8 * 8) = zero;
        }
    } else if (bid < 928) {
        int f = (bid - 784) * 256 + t;           // 0..36863
        int e    = f & 7;
        int l    = (f >> 3) & 63;
        int ch   = (f >> 9) & 3;
        int tap  = (f >> 11) % 9;
        int mt   = f / 18432;
        int oc = mt * 16 + (l & 15);
        int c  = ch * 32 + (l >> 4) * 8 + e;
        float v = (oc < NOC) ? rot_w[(size_t)oc * (Cdim * 9) + c * 9 + tap] : 0.f;
        wpk[f] = f2bf(v);
    } else {
        for (int i = t; i < 576; i += 256) {
            int e = i >> 6;              // cell 0..8
            int l = i & 63;              // c-pair
            int r = e / 3, s = e % 3;
            const float* w0p = weight + (size_t)(2 * l) * 16;
            uint4 v;
            v.x = pkh2(w0p[r * 4 + s],      w0p[r * 4 + s + 1]);
            v.y = pkh2(w0p[r * 4 + s + 4],  w0p[r * 4 + s + 5]);
            v.z = pkh2(w0p[16 + r * 4 + s],     w0p[16 + r * 4 + s + 1]);
            v.w = pkh2(w0p[16 + r * 4 + s + 4], w0p[16 + r * 4 + s + 5]);
            wtab[i] = v;
        }
    }
}

// ---------------------------------------------------------------------------
// Kernel 2 (FUSED conv+coef+apply). Block = one 16-px tile, 4 waves.
// Phase A (conv): wave wv owns K-chunk wv (32 channels); per tap 1 B-frag
//   (16B, xnh) + 2 A-frags (16B, L2-hot wpk, no LDS staging) + 2 MFMA.
//   Partials -> dsc[wv][px][20].
// Phase B (coef): tid<144 sums 4 partials, computes bilinear quads -> cq2,
//   cell idx bytes -> lidb. Never touches global.
// Phase C (apply): R14 structure — lane = c-pair, wave handles 4 px, batched
//   LDS reads (9 table quads + 9 coef pairs) then 36 fdot2+fma; x window from
//   L1-hot xnh. NCHW store via ot transpose.
// ---------------------------------------------------------------------------
__global__ __launch_bounds__(256) void fused_kernel(const short* __restrict__ xnh,
                                                    const short* __restrict__ wpk,
                                                    const float* __restrict__ rot_b,
                                                    const uint4* __restrict__ wtab,
                                                    float* __restrict__ out) {
    __shared__ uint4 wq4[9][64];     // fp16 weight quads            (9216 B)
    __shared__ float dsc[4 * 16 * 20];   // conv partials per wave   (5120 B)
    __shared__ uint2 cq2[144];       // coef pairs 16px x 9taps      (1152 B)
    __shared__ uint4 lidq[16];       // cell idx bytes [px][16]      ( 256 B)
    __shared__ float ot[16][130];    // [px][c] store transpose      (8320 B)

    const int tid  = threadIdx.x;
    const int lane = tid & 63;
    const int wv   = tid >> 6;       // 0..3

    for (int i = tid; i < 576; i += 256)          // stage weight table once
        ((uint4*)wq4)[i] = wtab[i];

    const int tile = blockIdx.x;                  // 0..2303
    const int b    = tile / 576;
    const int hw0  = (tile % 576) * 16;
    const int h    = hw0 / Wdim;
    const int w0   = hw0 % Wdim;

    // ---- Phase A: conv partials (wave wv = K-chunk wv) ----
    {
        const int px = lane & 15, kg = lane >> 4;
        f32x4 acc0 = {0,0,0,0};      // mt0 rows: oc = kg*4 + r
        f32x4 acc1 = {0,0,0,0};      // mt1 rows: oc = 16 + kg*4 + r
        const short* xb = xnh + (((size_t)b * 98 + h) * 98 + (w0 + px)) * 128
                          + wv * 32 + kg * 8;
        const short* wA = wpk + (size_t)wv * 512 + lane * 8;

        bf16x8 Bc  = *(const bf16x8*)(xb);
        bf16x8 A0c = *(const bf16x8*)(wA);
        bf16x8 A1c = *(const bf16x8*)(wA + 9 * 4 * 512);
#pragma unroll
        for (int tap = 0; tap < 9; ++tap) {
            bf16x8 Bn, A0n, A1n;
            if (tap < 8) {
                const int di = (tap + 1) / 3, dj = (tap + 1) % 3;
                Bn  = *(const bf16x8*)(xb + (di * 98 + dj) * 128);
                A0n = *(const bf16x8*)(wA + (size_t)(tap + 1) * 4 * 512);
                A1n = *(const bf16x8*)(wA + (size_t)(9 + tap + 1) * 4 * 512);
            }
            acc0 = __builtin_amdgcn_mfma_f32_16x16x32_bf16(A0c, Bc, acc0, 0, 0, 0);
            acc1 = __builtin_amdgcn_mfma_f32_16x16x32_bf16(A1c, Bc, acc1, 0, 0, 0);
            if (tap < 8) { Bc = Bn; A0c = A0n; A1c = A1n; }
        }
        float* ds = dsc + ((wv * 16) + px) * 20;
        *(f32x4*)(ds + kg * 4) = acc0;
        if (kg == 0) { ds[16] = acc1[0]; ds[17] = acc1[1]; }
    }
    __syncthreads();

    // ---- Phase B: reduce partials + coefs (tid < 144) ----
    if (tid < 144) {
        const int px = tid / 9;
        const int t9 = tid - px * 9;
        const int i = t9 / 3, j = t9 % 3;
        float ch = rot_b[2 * t9]     + (0.5f + (float)i);
        float cw = rot_b[2 * t9 + 1] + (0.5f + (float)j);
#pragma unroll
        for (int k = 0; k < 4; ++k) {
            const float* ds = dsc + ((k * 16) + px) * 20;
            ch += ds[2 * t9];
            cw += ds[2 * t9 + 1];
        }
        ch = fminf(fmaxf(ch, 0.f), 3.f);
        cw = fminf(fmaxf(cw, 0.f), 3.f);
        float h0f = floorf(ch), w0f = floorf(cw);
        float lh = ch - h0f, lw = cw - w0f;
        int h0 = (int)h0f, w0i = (int)w0f;
        float bh0 = 1.f - lh;
        float aw0 = 1.f - lw;
        if (h0 >= 3)  { h0 = 2;  bh0 = 0.f; }
        if (w0i >= 3) { w0i = 2; aw0 = 0.f; }
        float q00 = aw0 * bh0;
        float q01 = (1.f - aw0) * bh0;
        float q10 = aw0 * (1.f - bh0);
        float q11 = (1.f - aw0) * (1.f - bh0);
        uint2 cf;
        cf.x = pkh2(q00, q01);
        cf.y = pkh2(q10, q11);
        cq2[px * 9 + t9] = cf;
        ((unsigned char*)lidq)[px * 16 + t9] = (unsigned char)(h0 * 3 + w0i);
    }
    __syncthreads();

    // ---- Phase C: apply (wave wv = px group, lane = c-pair) ----
    const unsigned* xbase =
        (const unsigned*)(xnh + (((size_t)b * 98 + h) * 98 + (w0 + 4 * wv)) * 128) + lane;
    unsigned xw[3][6];
#pragma unroll
    for (int r = 0; r < 3; ++r)
#pragma unroll
        for (int j = 0; j < 6; ++j)
            xw[r][j] = xbase[(r * 98 + j) * 64];

    float acc0[4], acc1[4];
#pragma unroll
    for (int p = 0; p < 4; ++p) { acc0[p] = 0.f; acc1[p] = 0.f; }

#pragma unroll
    for (int pp = 0; pp < 4; ++pp) {
        const int p = 4 * wv + pp;
        uint4 lw = lidq[p];                      // one uniform read -> 9 indices
        uint4 g[9];
        uint2 cf[9];
#pragma unroll
        for (int t = 0; t < 9; ++t) {            // batched independent LDS reads
            unsigned idx = (((const unsigned*)&lw)[t >> 2] >> (8 * (t & 3))) & 0xFu;
            g[t]  = wq4[idx][lane];
            cf[t] = cq2[p * 9 + t];
        }
#pragma unroll
        for (int t = 0; t < 9; ++t) {
            unsigned xu = xw[t / 3][pp + (t % 3)];
            float x0 = __uint_as_float(xu << 16);
            float x1 = __uint_as_float(xu & 0xFFFF0000u);
            float s0 = __builtin_amdgcn_fdot2(__builtin_bit_cast(h2, cf[t].x),
                                              __builtin_bit_cast(h2, g[t].x), 0.f, false);
            s0 = __builtin_amdgcn_fdot2(__builtin_bit_cast(h2, cf[t].y),
                                        __builtin_bit_cast(h2, g[t].y), s0, false);
            float s1 = __builtin_amdgcn_fdot2(__builtin_bit_cast(h2, cf[t].x),
                                              __builtin_bit_cast(h2, g[t].z), 0.f, false);
            s1 = __builtin_amdgcn_fdot2(__builtin_bit_cast(h2, cf[t].y),
                                        __builtin_bit_cast(h2, g[t].w), s1, false);
            acc0[pp] = fmaf(s0, x0, acc0[pp]);
            acc1[pp] = fmaf(s1, x1, acc1[pp]);
        }
    }

    // transpose through LDS, then coalesced NCHW stores
#pragma unroll
    for (int pp = 0; pp < 4; ++pp)
        *(float2*)&ot[4 * wv + pp][2 * lane] = make_float2(acc0[pp], acc1[pp]);
    __syncthreads();

    const int px = tid & 15;
    const int cr = tid >> 4;                     // 0..15
    float* ob = out + (size_t)b * Cdim * HW + hw0 + px;
#pragma unroll
    for (int k = 0; k < 8; ++k) {
        int ci = cr * 8 + k;
        ob[(size_t)ci * HW] = ot[px][ci];
    }
}

// ---------------------------------------------------------------------------
extern "C" void kernel_launch(void* const* d_in, const int* in_sizes, int n_in,
                              void* d_out, int out_size, void* d_ws, size_t ws_size,
                              hipStream_t stream) {
    const float* x      = (const float*)d_in[0];
    const float* rot_w  = (const float*)d_in[1];
    const float* rot_b  = (const float*)d_in[2];
    const float* weight = (const float*)d_in[3];
    float* out = (float*)d_out;

    char* ws = (char*)d_ws;
    const size_t xnh_bytes = (size_t)Bdim * 98 * 98 * 128 * 2;   // 9,834,496
    const size_t wpk_bytes = (size_t)2 * 9 * 4 * 64 * 8 * 2;     //    73,728

    short* xnh  = (short*)ws;
    short* wpk  = (short*)(ws + xnh_bytes);
    uint4* wtab = (uint4*)(ws + xnh_bytes + wpk_bytes);          // 9,216 B

    prep_kernel<<<929, 256, 0, stream>>>(x, rot_w, weight, xnh, wpk, wtab);
    fused_kernel<<<2304, 256, 0, stream>>>(xnh, wpk, rot_b, wtab, out);
}